// Round 1
// 209.842 us; speedup vs baseline: 1.0191x; 1.0191x over previous
//
#include <hip/hip_runtime.h>
#include <math.h>

#define HH 512
#define WW 512
#define NCH 48
#define HWPIX (HH * WW)

#define TW 16            // tile width (pixels)
#define TH 8             // tile height
#define HW_HALO 18       // TW + 2
#define HH_HALO 10       // TH + 2
#define NHALO (HW_HALO * HH_HALO)   // 180 halo pixels
#define PSTRIDE 13       // float4 slots per halo pixel (12 + 1 pad)
#define ASTRIDE 12       // floats per pixel in packed A (9 + 3 pad, 16B-aligned)

// ---------------------------------------------------------------------------
// Kernel 1: precompute the 9 per-pixel stencil weights from Dt, with
//   - border zero-padding masks folded in (conv is SAME/zero-pad),
//   - 1/dg folded in, MSQ=0.1 folded into the center weight.
// Dt layout: (H, W, 3) = (a, c, b); rolls are PERIODIC (jnp.roll).
// A stored PIXEL-MAJOR, 12 floats per pixel (slots 0..8 used, 9..11 pad):
//   A[pix*12 + k] multiplies x[h-1+k/3, w-1+k%3].  One pixel's weights are
//   3 aligned float4 loads (vs 9 plane-strided dwords in the old layout).
// ---------------------------------------------------------------------------
__global__ __launch_bounds__(256) void compute_A_kernel(
    const float* __restrict__ Dt, const float* __restrict__ dg,
    float* __restrict__ A) {
  int pix = blockIdx.x * blockDim.x + threadIdx.x;
  int h = pix >> 9;
  int w = pix & (WW - 1);
  int hm = (h == 0) ? HH - 1 : h - 1;
  int hp = (h == HH - 1) ? 0 : h + 1;
  int wm = (w == 0) ? WW - 1 : w - 1;
  int wp = (w == WW - 1) ? 0 : w + 1;

  float aC, cC, bC, cL, bL, cR, bR, aU, bU, aD, bD;
  float bUL, bUR, bDL, bDR;
  {
    int p;
    p = (h * WW + w) * 3;   aC = Dt[p]; cC = Dt[p + 1]; bC = Dt[p + 2];
    p = (h * WW + wm) * 3;  cL = Dt[p + 1]; bL = Dt[p + 2];
    p = (h * WW + wp) * 3;  cR = Dt[p + 1]; bR = Dt[p + 2];
    p = (hm * WW + w) * 3;  aU = Dt[p]; bU = Dt[p + 2];
    p = (hp * WW + w) * 3;  aD = Dt[p]; bD = Dt[p + 2];
    p = (hm * WW + wm) * 3; bUL = Dt[p + 2];
    p = (hm * WW + wp) * 3; bUR = Dt[p + 2];
    p = (hp * WW + wm) * 3; bDL = Dt[p + 2];
    p = (hp * WW + wp) * 3; bDR = Dt[p + 2];
  }

  float A0 = (fabsf(bDL) - bDL + fabsf(bC) - bC) * 0.25f;
  float A1 = (cL + cC - fabsf(bL) - fabsf(bC)) * 0.5f;
  float A2 = (fabsf(bUL) + bUL + fabsf(bC) + bC) * 0.25f;
  float A3 = (aD + aC - fabsf(bD) - fabsf(bC)) * 0.5f;
  float A4 = -(aD + 2.f * aC + aU) * 0.5f
             - (fabsf(bDL) - bDL + fabsf(bUL) + bUL) * 0.25f
             - (fabsf(bDR) + bDR + fabsf(bUR) - bUR) * 0.25f
             + (fabsf(bD) + fabsf(bU) + fabsf(bR) + fabsf(bL) + 2.f * fabsf(bC)) * 0.5f
             - (cR + 2.f * cC + cL) * 0.5f;
  float A5 = (aU + aC - fabsf(bU) - fabsf(bC)) * 0.5f;
  float A6 = (fabsf(bDR) + bDR + fabsf(bC) + bC) * 0.25f;
  float A7 = (cR + cC - fabsf(bR) - fabsf(bC)) * 0.5f;
  float A8 = (fabsf(bUR) - bUR + fabsf(bC) - bC) * 0.25f;

  bool ru = (h > 0), rd = (h < HH - 1), cl = (w > 0), cr = (w < WW - 1);
  if (!(ru && cl)) A0 = 0.f;
  if (!ru)         A1 = 0.f;
  if (!(ru && cr)) A2 = 0.f;
  if (!cl)         A3 = 0.f;
  if (!cr)         A5 = 0.f;
  if (!(rd && cl)) A6 = 0.f;
  if (!rd)         A7 = 0.f;
  if (!(rd && cr)) A8 = 0.f;

  float g = 1.0f / dg[pix];
  float4 o0 = make_float4(A0 * g, A1 * g, A2 * g, A3 * g);
  float4 o1 = make_float4(A4 * g + 0.1f, A5 * g, A6 * g, A7 * g);
  float4 o2 = make_float4(A8 * g, 0.f, 0.f, 0.f);
  float4* Ao = (float4*)A + (size_t)pix * 3;
  Ao[0] = o0;
  Ao[1] = o1;
  Ao[2] = o2;
}

// ---------------------------------------------------------------------------
// Fused Euler step, 16x8 tile, 2-pixel register blocking, lse-once staging.
// Phase 1: threads 0..179 each stage one halo pixel's 12 float4 from global
//   (periodic wrap) into LDS AND compute its 48-channel logsumexp in-register.
//   NEW: the per-pair stencil weights (packed A, 3x float4) and hinv
//   (3x float2) are prefetched BEFORE the barrier so their latency hides
//   under the lse compute + barrier wait instead of stalling phase 2's
//   lead-in (was 24 scattered dwords issued right after __syncthreads).
// Phase 2: quad (4 threads, sub = interleaved chunk j*4+sub) handles a
//   horizontally-adjacent pixel PAIR: 3x4 LDS patch per chunk serves both
//   pixels' 3x3 stencils (18 b128/pixel).
//   val = sum_k Aeff[k]*x[nbr_k] + 0.5*(ha*v0^2 + hc*v1^2) + hb*v0*v1
//   v0 = logp[h+1,w]-logp[h,w], v1 = logp[h,w+1]-logp[h,w]  (periodic)
//   x_next = x + 0.2 * clip(val - mean_ch(val), +-1e8)
// XCD-band swizzle: XCD k (= b%8) gets tile rows [8k,8k+8) = pixel rows
// [64k, 64k+64), keeping vertical halo reuse inside one per-XCD L2.
// ---------------------------------------------------------------------------
__global__ __launch_bounds__(256, 4) void step_fused_kernel(
    const float* __restrict__ x, const float* __restrict__ A,
    const float* __restrict__ hinv, float* __restrict__ xn) {
  __shared__ float4 tile[NHALO * PSTRIDE];   // 180*13*16 = 37,440 B
  __shared__ float lse_s[NHALO];             // + 720 B

  int b = blockIdx.x;
  int tile_id = (b & 7) * 256 + (b >> 3);    // 2048 tiles, 64 rows x 32 cols
  int th0 = (tile_id >> 5) * TH;
  int tw0 = (tile_id & 31) * TW;

  int t = threadIdx.x;
  // phase-2 indices computed up-front (needed for the prefetch)
  int sub = t & 3;                            // interleaved chunk set
  int pair = t >> 2;                          // 0..63
  int pr = pair >> 3;                         // tile row 0..7
  int pc0 = (pair & 7) * 2;                   // even tile col 0..14
  int pix0 = (th0 + pr) * WW + (tw0 + pc0);
  int pix1 = pix0 + 1;

  // ---- Phase 1a: issue halo staging loads (critical path: feeds lse) ----
  float4 v[12];
  bool stager = (t < NHALO);
  if (stager) {
    int r = t / HW_HALO;
    int c = t - r * HW_HALO;
    int gh = (th0 + r - 1) & (HH - 1);       // periodic wrap
    int gw = (tw0 + c - 1) & (WW - 1);
    const float4* src = (const float4*)x + (size_t)(gh * WW + gw) * 12;
#pragma unroll
    for (int i = 0; i < 12; i++) v[i] = src[i];
  }

  // ---- Phase 1b: prefetch packed stencil weights + hinv (pre-barrier) ----
  const float4* ap0 = (const float4*)A + (size_t)pix0 * 3;
  const float4* ap1 = (const float4*)A + (size_t)pix1 * 3;
  float4 wA0 = ap0[0], wB0 = ap0[1], wC0 = ap0[2];
  float4 wA1 = ap1[0], wB1 = ap1[1], wC1 = ap1[2];
  // 6 consecutive floats for the pair; pix0 is even so base is 8B-aligned
  const float2* hp = (const float2*)(hinv + (size_t)pix0 * 3);
  float2 h01 = hp[0], h23 = hp[1], h45 = hp[2];

  // ---- Phase 1c: lse (4-lane-parallel chains) + LDS staging writes ----
  if (stager) {
    float4 mv = v[0];
#pragma unroll
    for (int i = 1; i < 12; i++) {
      mv.x = fmaxf(mv.x, v[i].x); mv.y = fmaxf(mv.y, v[i].y);
      mv.z = fmaxf(mv.z, v[i].z); mv.w = fmaxf(mv.w, v[i].w);
    }
    float m = fmaxf(fmaxf(mv.x, mv.y), fmaxf(mv.z, mv.w));
    float sx = 0.f, sy = 0.f, sz = 0.f, sw = 0.f;
#pragma unroll
    for (int i = 0; i < 12; i++) {
      sx += __expf(v[i].x - m); sy += __expf(v[i].y - m);
      sz += __expf(v[i].z - m); sw += __expf(v[i].w - m);
      tile[t * PSTRIDE + i] = v[i];
    }
    lse_s[t] = m + __logf((sx + sy) + (sz + sw));
  }
  __syncthreads();

  // ---- Phase 2: pixel-pair compute --------------------------------------
  float wt0[9] = {wA0.x, wA0.y, wA0.z, wA0.w, wB0.x, wB0.y, wB0.z, wB0.w, wC0.x};
  float wt1[9] = {wA1.x, wA1.y, wA1.z, wA1.w, wB1.x, wB1.y, wB1.z, wB1.w, wC1.x};
  float ha0 = h01.x, hc0 = h01.y, hb0 = h23.x;
  float ha1 = h23.y, hc1 = h45.x, hb1 = h45.y;

  // lse taps (halo coords: center of px0 = (pr+1, pc0+1))
  int lc0 = (pr + 1) * HW_HALO + (pc0 + 1);
  float l0C = lse_s[lc0];
  float l0R = lse_s[lc0 + 1];                 // = l1C
  float l1R = lse_s[lc0 + 2];
  float l0D = lse_s[lc0 + HW_HALO];
  float l1D = lse_s[lc0 + HW_HALO + 1];
  float dld0 = l0C - l0D, dlr0 = l0C - l0R;
  float dld1 = l0R - l1D, dlr1 = l0R - l1R;

  // LDS float4-offsets of the 3x4 patch (rows pr..pr+2, cols pc0..pc0+3)
  int poff[3][4];
#pragma unroll
  for (int dr = 0; dr < 3; dr++)
#pragma unroll
    for (int dc = 0; dc < 4; dc++)
      poff[dr][dc] = ((pr + dr) * HW_HALO + pc0 + dc) * PSTRIDE;

  float4 vals0[3], vals1[3];
  float sum0 = 0.f, sum1 = 0.f;
#pragma unroll
  for (int j = 0; j < 3; j++) {
    int ch = j * 4 + sub;
    float4 q[3][4];
#pragma unroll
    for (int dr = 0; dr < 3; dr++)
#pragma unroll
      for (int dc = 0; dc < 4; dc++) q[dr][dc] = tile[poff[dr][dc] + ch];

    float4 val0, val1;
#define COMP(f)                                                                \
    {                                                                          \
      float s0_ = wt0[0] * q[0][0].f + wt0[1] * q[0][1].f + wt0[2] * q[0][2].f \
                + wt0[3] * q[1][0].f + wt0[4] * q[1][1].f + wt0[5] * q[1][2].f \
                + wt0[6] * q[2][0].f + wt0[7] * q[2][1].f + wt0[8] * q[2][2].f;\
      float v00 = q[2][1].f - q[1][1].f + dld0;                                \
      float v10 = q[1][2].f - q[1][1].f + dlr0;                                \
      float vv0 = s0_ + 0.5f * (ha0 * v00 * v00 + hc0 * v10 * v10) +           \
                  hb0 * (v00 * v10);                                           \
      val0.f = vv0; sum0 += vv0;                                               \
      float s1_ = wt1[0] * q[0][1].f + wt1[1] * q[0][2].f + wt1[2] * q[0][3].f \
                + wt1[3] * q[1][1].f + wt1[4] * q[1][2].f + wt1[5] * q[1][3].f \
                + wt1[6] * q[2][1].f + wt1[7] * q[2][2].f + wt1[8] * q[2][3].f;\
      float v01 = q[2][2].f - q[1][2].f + dld1;                                \
      float v11 = q[1][3].f - q[1][2].f + dlr1;                                \
      float vv1 = s1_ + 0.5f * (ha1 * v01 * v01 + hc1 * v11 * v11) +           \
                  hb1 * (v01 * v11);                                           \
      val1.f = vv1; sum1 += vv1;                                               \
    }
    COMP(x) COMP(y) COMP(z) COMP(w)
#undef COMP
    vals0[j] = val0;
    vals1[j] = val1;
  }

  // channel mean across the 4-thread quad (48 channels per pixel)
  sum0 += __shfl_xor(sum0, 1); sum0 += __shfl_xor(sum0, 2);
  sum1 += __shfl_xor(sum1, 1); sum1 += __shfl_xor(sum1, 2);
  float mean0 = sum0 * (1.0f / 48.0f);
  float mean1 = sum1 * (1.0f / 48.0f);

  // centers re-read from LDS (saves 24 VGPRs vs holding them live)
  int cen0 = lc0 * PSTRIDE;                   // px0 center halo offset
  float4* op0 = (float4*)(xn + (size_t)pix0 * NCH);
  float4* op1 = op0 + 12;
#pragma unroll
  for (int j = 0; j < 3; j++) {
    int ch = j * 4 + sub;
    float4 c0 = tile[cen0 + ch];
    float4 c1 = tile[cen0 + PSTRIDE + ch];
    float4 r0, r1;
    r0.x = c0.x + 0.2f * fminf(fmaxf(vals0[j].x - mean0, -1e8f), 1e8f);
    r0.y = c0.y + 0.2f * fminf(fmaxf(vals0[j].y - mean0, -1e8f), 1e8f);
    r0.z = c0.z + 0.2f * fminf(fmaxf(vals0[j].z - mean0, -1e8f), 1e8f);
    r0.w = c0.w + 0.2f * fminf(fmaxf(vals0[j].w - mean0, -1e8f), 1e8f);
    r1.x = c1.x + 0.2f * fminf(fmaxf(vals1[j].x - mean1, -1e8f), 1e8f);
    r1.y = c1.y + 0.2f * fminf(fmaxf(vals1[j].y - mean1, -1e8f), 1e8f);
    r1.z = c1.z + 0.2f * fminf(fmaxf(vals1[j].z - mean1, -1e8f), 1e8f);
    r1.w = c1.w + 0.2f * fminf(fmaxf(vals1[j].w - mean1, -1e8f), 1e8f);
    op0[ch] = r0;
    op1[ch] = r1;
  }
}

// ---------------------------------------------------------------------------
// Host launcher.  inputs: v (H,W,48), Dt (H,W,3), dg (H,W,1), hinv (H,W,3)
// ws layout: A[12*HW packed] | xbuf[HW*48]   (~63 MB)
// ping-pong: v -> out -> ws -> out -> ws -> out  (5 steps)
// ---------------------------------------------------------------------------
extern "C" void kernel_launch(void* const* d_in, const int* in_sizes, int n_in,
                              void* d_out, int out_size, void* d_ws, size_t ws_size,
                              hipStream_t stream) {
  const float* v    = (const float*)d_in[0];
  const float* Dt   = (const float*)d_in[1];
  const float* dg   = (const float*)d_in[2];
  const float* hinv = (const float*)d_in[3];
  float* out = (float*)d_out;

  float* A    = (float*)d_ws;
  float* xbuf = A + (size_t)ASTRIDE * HWPIX;

  compute_A_kernel<<<dim3(HWPIX / 256), dim3(256), 0, stream>>>(Dt, dg, A);

  const float* cur = v;
  float* nxt = out;
  for (int s = 0; s < 5; s++) {
    step_fused_kernel<<<dim3(HWPIX / 128), dim3(256), 0, stream>>>(cur, A, hinv, nxt);
    if (s == 0) {
      cur = out;
      nxt = xbuf;
    } else {
      float* t = (float*)cur;
      cur = nxt;
      nxt = t;
    }
  }
}